// Round 11
// baseline (133.545 us; speedup 1.0000x reference)
//
#include <hip/hip_runtime.h>
#include <hip/hip_bf16.h>

#define N_   8192
#define DIM_ 512
#define DK_  128
#define DV_  512
#define L2E_ 1.44269504088896f
#define NCH_ 512          // scan chunks
#define CHR_ 16           // rows per chunk

typedef short short8 __attribute__((ext_vector_type(8)));
typedef float f32x4  __attribute__((ext_vector_type(4)));
typedef float f32x2  __attribute__((ext_vector_type(2)));

__device__ __forceinline__ float fexp2(float x) { return __builtin_amdgcn_exp2f(x); }

__device__ __forceinline__ ushort f2bf(float f) {
    union { float f; unsigned u; } v; v.f = f;
    unsigned u = v.u;
    return (ushort)((u + 0x7FFFu + ((u >> 16) & 1u)) >> 16);
}
__device__ __forceinline__ float bf2f(ushort u) { return __uint_as_float(((unsigned)u) << 16); }
__device__ __forceinline__ float decode_max(unsigned u) {
    return __uint_as_float((u & 0x80000000u) ? (u ^ 0x80000000u) : ~u);
}

// ---- kernel 1: u1/u2/c1/c2 (blocks 0-1), zero scal max, wv_w -> bf16 (blocks 2-129) ----
__global__ __launch_bounds__(256) void prep_kernel(const float* __restrict__ w_w,
                            const float* __restrict__ w_b, const float* __restrict__ a,
                            const float* __restrict__ wv_w,
                            float* __restrict__ u1, float* __restrict__ u2,
                            float* __restrict__ scal, ushort* __restrict__ wvbf) {
    int bid = blockIdx.x, t = threadIdx.x;
    if (bid < 2) {
        int d = bid * 256 + t;
        float s1 = 0.f, s2 = 0.f;
        for (int k = 0; k < DK_; ++k) {
            float w = w_w[k * DIM_ + d];
            s1 += w * a[k];
            s2 += w * a[DK_ + k];
        }
        u1[d] = s1; u2[d] = s2;
        if (d == 0) { float c = 0.f; for (int k = 0; k < DK_; ++k) c += w_b[k] * a[k];        scal[0] = c; }
        if (d == 1) { float c = 0.f; for (int k = 0; k < DK_; ++k) c += w_b[k] * a[DK_ + k];  scal[1] = c; }
        if (d == 2) ((unsigned*)scal)[3] = 0u;
    } else {
        int idx = (bid - 2) * 2048 + t * 8;
        f32x4 lo = *(const f32x4*)(wv_w + idx);
        f32x4 hi = *(const f32x4*)(wv_w + idx + 4);
        short8 f;
#pragma unroll
        for (int e = 0; e < 4; ++e) { f[e] = (short)f2bf(lo[e]); f[e + 4] = (short)f2bf(hi[e]); }
        *(short8*)(wvbf + idx) = f;
    }
}

// ---- kernel 2: e_src[i], e_dst[i], bf16 copy of x, zero rank/ki/res ----
__global__ __launch_bounds__(256) void e_kernel(const float* __restrict__ x,
        const float* __restrict__ u1, const float* __restrict__ u2,
        const float* __restrict__ scal, float* __restrict__ e_src, float* __restrict__ e_dst,
        ushort* __restrict__ xbf, int* __restrict__ rank, int* __restrict__ ki,
        int* __restrict__ res) {
    int wid = threadIdx.x >> 6, lane = threadIdx.x & 63;
    int row = blockIdx.x * 4 + wid;
    const float* xr = x + (size_t)row * DIM_;
    int d0 = lane * 8;
    f32x4 xa = *(const f32x4*)(xr + d0);
    f32x4 xb = *(const f32x4*)(xr + d0 + 4);
    f32x4 ua = *(const f32x4*)(u1 + d0);
    f32x4 ub = *(const f32x4*)(u1 + d0 + 4);
    f32x4 va = *(const f32x4*)(u2 + d0);
    f32x4 vb = *(const f32x4*)(u2 + d0 + 4);
    short8 xv;
#pragma unroll
    for (int e = 0; e < 4; ++e) { xv[e] = (short)f2bf(xa[e]); xv[e + 4] = (short)f2bf(xb[e]); }
    *(short8*)(xbf + (size_t)row * DIM_ + d0) = xv;
    float s1 = 0.f, s2 = 0.f;
#pragma unroll
    for (int e = 0; e < 4; ++e) {
        s1 += xa[e] * ua[e] + xb[e] * ub[e];
        s2 += xa[e] * va[e] + xb[e] * vb[e];
    }
    for (int off = 32; off; off >>= 1) { s1 += __shfl_xor(s1, off); s2 += __shfl_xor(s2, off); }
    if (lane == 0) {
        e_src[row] = s1 + scal[0];
        e_dst[row] = s2 + scal[1];
    }
    if (lane == 1) rank[row] = 0;
    if (lane == 2) ki[row] = 0;
    if (lane == 3) res[row] = 0;
}

// ---- kernel 3 (fused): blocks 0-511 = counting ranks (+max); blocks 512-767 = V GEMM ----
__global__ __launch_bounds__(256) void rankv_kernel(const float* __restrict__ e_dst,
        const float* __restrict__ e_src, int* __restrict__ rank, int* __restrict__ ki,
        int* __restrict__ res, float* __restrict__ scal,
        const ushort* __restrict__ xbf, const ushort* __restrict__ wvbf,
        const float* __restrict__ wv_b, ushort* __restrict__ V) {
    int bid = blockIdx.x, t = threadIdx.x;
    if (bid < 512) {
        __shared__ float ed[512];
        __shared__ float esl[512];
        __shared__ float red[4];
        int bx = bid & 31, by = bid >> 5;
        int rbase = by * 512;
        for (int q = t; q < 512; q += 256) { ed[q] = e_dst[rbase + q]; esl[q] = e_src[rbase + q]; }
        __syncthreads();
        if (bx == 0) {
            float m = fmaxf(ed[t], ed[t + 256]);
            for (int off = 32; off; off >>= 1) m = fmaxf(m, __shfl_xor(m, off));
            if ((t & 63) == 0) red[t >> 6] = m;
            __syncthreads();
            if (t == 0) {
                m = fmaxf(fmaxf(red[0], red[1]), fmaxf(red[2], red[3]));
                unsigned u = __float_as_uint(m);
                u ^= (unsigned)(((int)u >> 31)) | 0x80000000u;
                atomicMax(((unsigned*)scal) + 3, u);
            }
        }
        int j = bx * 256 + t;
        float kj = e_dst[j];
        float kei = -e_src[j];
        float kes = e_src[j];
        int cj = 0, ci = 0, ce = 0;
#pragma unroll 8
        for (int q = 0; q < 512; ++q) {
            float v = ed[q];
            float w = esl[q];
            int r = rbase + q;
            cj += (v < kj) || (v == kj && r < j);
            ci += (v < kei);
            ce += (w < kes) || (w == kes && r < j);
        }
        atomicAdd(rank + j, cj);
        atomicAdd(ki + j, ci);
        atomicAdd(res + j, ce);
    } else {
        int vb = bid - 512;
        int wid = t >> 6, lane = t & 63;
        int ln16 = lane & 15, kg = lane >> 4;
        int jb = (vb & 31) * 256 + wid * 64;
        int cb = (vb >> 5) * 64;
        f32x4 acc[4][4] = {};
        float bias[4];
#pragma unroll
        for (int ng = 0; ng < 4; ++ng) bias[ng] = wv_b[cb + ng * 16 + ln16];
        for (int k0 = 0; k0 < DIM_; k0 += 32) {
            int kk = k0 + kg * 8;
            short8 afr[4], bfr[4];
#pragma unroll
            for (int mg = 0; mg < 4; ++mg)
                afr[mg] = *(const short8*)(xbf + (size_t)(jb + mg * 16 + ln16) * DIM_ + kk);
#pragma unroll
            for (int ng = 0; ng < 4; ++ng)
                bfr[ng] = *(const short8*)(wvbf + (size_t)(cb + ng * 16 + ln16) * DIM_ + kk);
#pragma unroll
            for (int mg = 0; mg < 4; ++mg)
#pragma unroll
                for (int ng = 0; ng < 4; ++ng)
                    acc[mg][ng] = __builtin_amdgcn_mfma_f32_16x16x32_bf16(afr[mg], bfr[ng], acc[mg][ng], 0, 0, 0);
        }
#pragma unroll
        for (int mg = 0; mg < 4; ++mg)
#pragma unroll
            for (int ng = 0; ng < 4; ++ng)
#pragma unroll
                for (int r = 0; r < 4; ++r) {
                    int j = jb + mg * 16 + kg * 4 + r;
                    int c = cb + ng * 16 + ln16;
                    V[(size_t)j * DV_ + c] = f2bf(acc[mg][ng][r] + bias[ng]);
                }
    }
}

// ---- kernel 4: scatter perm, perm_es, G factors in sorted order ----
__global__ __launch_bounds__(256) void scatter_kernel(const float* __restrict__ e_dst,
        const int* __restrict__ rank, const int* __restrict__ res, const float* __restrict__ scal,
        int* __restrict__ perm, int* __restrict__ perm_es,
        float* __restrict__ Gs1, float* __restrict__ Gs2) {
    int j = blockIdx.x * 256 + threadIdx.x;
    float M = decode_max(((const unsigned*)scal)[3]);
    int rk = rank[j];
    float d = (e_dst[j] - M) * L2E_;
    perm[rk] = j;
    perm_es[res[j]] = j;
    Gs1[rk] = fexp2(d);
    Gs2[rk] = fexp2(0.01f * d);
}

// ---- kernel 5: chunk totals only (C1, C2, z-totals); grid 1024 = 512ch x 2half ----
__global__ __launch_bounds__(256) void ctot_kernel(const ushort* __restrict__ V,
        const int* __restrict__ perm, const float* __restrict__ Gs1, const float* __restrict__ Gs2,
        float* __restrict__ C1, float* __restrict__ C2,
        float* __restrict__ C1z, float* __restrict__ C2z) {
    int ch = blockIdx.x >> 1, half = blockIdx.x & 1;
    int t = threadIdx.x;
    int c = half * 256 + t;
    int k0 = ch * CHR_;
    int   jj[CHR_];
    float g1[CHR_], g2[CHR_], v[CHR_];
#pragma unroll
    for (int r = 0; r < CHR_; ++r) { jj[r] = perm[k0 + r]; g1[r] = Gs1[k0 + r]; g2[r] = Gs2[k0 + r]; }
#pragma unroll
    for (int r = 0; r < CHR_; ++r) v[r] = bf2f(V[(size_t)jj[r] * DV_ + c]);
    float t1 = 0.f, t2 = 0.f;
#pragma unroll
    for (int r = 0; r < CHR_; ++r) { t1 += g1[r] * v[r]; t2 += g2[r] * v[r]; }
    C1[ch * 512 + c] = t1; C2[ch * 512 + c] = t2;
    if (half == 0 && t == 0) {
        float z1t = 0.f, z2t = 0.f;
#pragma unroll
        for (int r = 0; r < CHR_; ++r) { z1t += g1[r]; z2t += g2[r]; }
        C1z[ch] = z1t; C2z[ch] = z2t;
    }
}

// ---- kernel 6: carries. b<64: excl prefix C2; b<128: excl suffix C1; b=128/129: z ----
__global__ __launch_bounds__(256) void p2_kernel(const float* __restrict__ C1,
        const float* __restrict__ C2, const float* __restrict__ C1z, const float* __restrict__ C2z,
        float* __restrict__ pc2, float* __restrict__ scs,
        float* __restrict__ zc2, float* __restrict__ zc1) {
    int b = blockIdx.x, t = threadIdx.x;
    if (b < 64) {
        int colL = t >> 5, s = t & 31;
        int c = b * 8 + colL;
        int base = s * 16;
        float v[16]; float seg = 0.f;
#pragma unroll
        for (int q = 0; q < 16; ++q) { v[q] = C2[(base + q) * 512 + c]; seg += v[q]; }
        float x = seg;
#pragma unroll
        for (int d = 1; d < 32; d <<= 1) { float y = __shfl_up(x, d, 32); if (s >= d) x += y; }
        float run = x - seg;
#pragma unroll
        for (int q = 0; q < 16; ++q) { pc2[(base + q) * 512 + c] = run; run += v[q]; }
        if (s == 31) pc2[NCH_ * 512 + c] = run;
    } else if (b < 128) {
        int colL = t >> 5, s = t & 31;
        int c = (b - 64) * 8 + colL;
        int base = s * 16;
        float v[16]; float seg = 0.f;
#pragma unroll
        for (int q = 0; q < 16; ++q) { v[q] = C1[(base + q) * 512 + c]; seg += v[q]; }
        float x = seg;
#pragma unroll
        for (int d = 1; d < 32; d <<= 1) { float y = __shfl_down(x, d, 32); if (s + d < 32) x += y; }
        float fwd = 0.f;
#pragma unroll
        for (int q = 0; q < 16; ++q) { fwd += v[q]; scs[(base + q) * 512 + c] = x - fwd; }
        if (s == 31) scs[NCH_ * 512 + c] = 0.f;
    } else {
        __shared__ float wt[4];
        bool pre = (b == 128);
        float v0 = pre ? C2z[t * 2] : C1z[t * 2];
        float v1 = pre ? C2z[t * 2 + 1] : C1z[t * 2 + 1];
        float seg = v0 + v1;
        int lane = t & 63, w = t >> 6;
        float x = seg;
        if (pre) {
#pragma unroll
            for (int d = 1; d < 64; d <<= 1) { float y = __shfl_up(x, d); if (lane >= d) x += y; }
            if (lane == 63) wt[w] = x;
        } else {
#pragma unroll
            for (int d = 1; d < 64; d <<= 1) { float y = __shfl_down(x, d); if (lane + d < 64) x += y; }
            if (lane == 0) wt[w] = x;
        }
        __syncthreads();
        float off = 0.f;
        if (pre) {
            for (int u = 0; u < w; ++u) off += wt[u];
            float run = off + (x - seg);
            zc2[t * 2] = run; run += v0; zc2[t * 2 + 1] = run;
            if (t == 255) zc2[NCH_] = off + x;
        } else {
            for (int u = w + 1; u < 4; ++u) off += wt[u];
            float S = off + x;                 // inclusive suffix from chunk t*2
            zc1[t * 2]     = S - v0;           // exclusive
            zc1[t * 2 + 1] = S - v0 - v1;
            if (t == 255) zc1[NCH_] = 0.f;
        }
    }
}

// ---- kernel 7: out rows in es-rank order; locals rebuilt from V/Gs/perm in registers ----
__global__ __launch_bounds__(256) void out_kernel(const float* __restrict__ e_src,
        const float* __restrict__ scal, const int* __restrict__ ki,
        const int* __restrict__ perm_es, const int* __restrict__ perm,
        const float* __restrict__ Gs1, const float* __restrict__ Gs2,
        const float* __restrict__ zc2, const float* __restrict__ zc1,
        const float* __restrict__ pc2, const float* __restrict__ scs,
        const ushort* __restrict__ V, float* __restrict__ out) {
    int t = threadIdx.x;
    float M = decode_max(((const unsigned*)scal)[3]);
    int idx0 = blockIdx.x * 16;
    int c2 = t * 2;
    for (int q = 0; q < 16; ++q) {
        int i = perm_es[idx0 + q];
        float es = e_src[i];
        float tt = es + M;
        float m = fmaxf(tt, 0.01f * tt);
        float F1 = fexp2((tt - m) * L2E_);
        float F2 = fexp2((0.01f * tt - m) * L2E_);
        int lo = ki[i];
        int ch = lo >> 4;
        int k0 = ch << 4;
        float a2l0 = 0.f, a2l1 = 0.f, s1l0 = 0.f, s1l1 = 0.f, z2l = 0.f, z1l = 0.f;
        if (k0 < N_) {
#pragma unroll 4
            for (int r = 0; r < CHR_; ++r) {
                int k = k0 + r;
                int j = perm[k];
                float g1 = Gs1[k], g2 = Gs2[k];
                unsigned pv = *(const unsigned*)(V + (size_t)j * DV_ + c2);
                float v0 = bf2f((ushort)(pv & 0xFFFFu));
                float v1 = bf2f((ushort)(pv >> 16));
                if (k < lo) { a2l0 += g2 * v0; a2l1 += g2 * v1; z2l += g2; }
                else        { s1l0 += g1 * v0; s1l1 += g1 * v1; z1l += g1; }
            }
        }
        float z = F2 * (zc2[ch] + z2l) + F1 * (zc1[ch] + z1l);
        float rz = 1.0f / z;
        f32x2 cp = *(const f32x2*)(pc2 + ch * 512 + c2);
        f32x2 cs = *(const f32x2*)(scs + ch * 512 + c2);
        out[(size_t)i * DV_ + c2]     = (F2 * (cp[0] + a2l0) + F1 * (cs[0] + s1l0)) * rz;
        out[(size_t)i * DV_ + c2 + 1] = (F2 * (cp[1] + a2l1) + F1 * (cs[1] + s1l1)) * rz;
    }
}

extern "C" void kernel_launch(void* const* d_in, const int* in_sizes, int n_in,
                              void* d_out, int out_size, void* d_ws, size_t ws_size,
                              hipStream_t stream) {
    const float* x    = (const float*)d_in[0];
    const float* w_w  = (const float*)d_in[1];
    const float* w_b  = (const float*)d_in[2];
    const float* wv_w = (const float*)d_in[3];
    const float* wv_b = (const float*)d_in[4];
    const float* a    = (const float*)d_in[5];
    float* out = (float*)d_out;
    char* ws = (char*)d_ws;

    ushort* V    = (ushort*)(ws);                        // 8 MiB
    ushort* xbf  = (ushort*)(ws + 8388608);              // 8 MiB
    char*   sm   = ws + 16777216;                        // small-array region
    float*  u1      = (float*)(sm);
    float*  u2      = (float*)(sm + 2048);
    float*  e_src   = (float*)(sm + 4096);
    float*  e_dst   = (float*)(sm + 36864);
    float*  scal    = (float*)(sm + 69632);              // [0]=c1 [1]=c2 [3]=max(uint)
    float*  Gs1     = (float*)(sm + 69888);
    float*  Gs2     = (float*)(sm + 102656);
    float*  C1      = (float*)(sm + 135424);             // 512*512*4 = 1 MiB
    float*  C2      = (float*)(sm + 1184000);
    float*  pc2     = (float*)(sm + 2232576);            // 513*512*4 (pad to 1,051,648)
    float*  scs     = (float*)(sm + 3284224);
    float*  C1z     = (float*)(sm + 4335872);            // 2 KiB
    float*  C2z     = (float*)(sm + 4337920);
    float*  zc2     = (float*)(sm + 4339968);            // 513 f (pad 4096)
    float*  zc1     = (float*)(sm + 4344064);
    int*    perm    = (int*)  (sm + 4348160);
    int*    rank    = (int*)  (sm + 4380928);
    int*    ki      = (int*)  (sm + 4413696);
    int*    res     = (int*)  (sm + 4446464);
    int*    perm_es = (int*)  (sm + 4479232);
    ushort* wvbf    = (ushort*)(sm + 4512000);           // 512 KiB

    hipLaunchKernelGGL(prep_kernel,    dim3(130),     dim3(256), 0, stream, w_w, w_b, a, wv_w, u1, u2, scal, wvbf);
    hipLaunchKernelGGL(e_kernel,       dim3(N_ / 4),  dim3(256), 0, stream, x, u1, u2, scal, e_src, e_dst, xbf, rank, ki, res);
    hipLaunchKernelGGL(rankv_kernel,   dim3(768),     dim3(256), 0, stream, e_dst, e_src, rank, ki, res, scal, xbf, wvbf, wv_b, V);
    hipLaunchKernelGGL(scatter_kernel, dim3(32),      dim3(256), 0, stream, e_dst, rank, res, scal, perm, perm_es, Gs1, Gs2);
    hipLaunchKernelGGL(ctot_kernel,    dim3(1024),    dim3(256), 0, stream, V, perm, Gs1, Gs2, C1, C2, C1z, C2z);
    hipLaunchKernelGGL(p2_kernel,      dim3(130),     dim3(256), 0, stream, C1, C2, C1z, C2z, pc2, scs, zc2, zc1);
    hipLaunchKernelGGL(out_kernel,     dim3(N_ / 16), dim3(256), 0, stream, e_src, scal, ki, perm_es, perm, Gs1, Gs2, zc2, zc1, pc2, scs, V, out);
}

// Round 12
// 82.224 us; speedup vs baseline: 1.6242x; 1.6242x over previous
//
#include <hip/hip_runtime.h>
#include <hip/hip_bf16.h>

#define N_   8192
#define DIM_ 512
#define DK_  128
#define DV_  512
#define L2E_ 1.44269504088896f
#define NCH_ 512          // scan chunks
#define CHR_ 16           // rows per chunk

typedef short short8 __attribute__((ext_vector_type(8)));
typedef float f32x4  __attribute__((ext_vector_type(4)));
typedef float f32x2  __attribute__((ext_vector_type(2)));
typedef unsigned u32x2 __attribute__((ext_vector_type(2)));

__device__ __forceinline__ float fexp2(float x) { return __builtin_amdgcn_exp2f(x); }

__device__ __forceinline__ ushort f2bf(float f) {
    union { float f; unsigned u; } v; v.f = f;
    unsigned u = v.u;
    return (ushort)((u + 0x7FFFu + ((u >> 16) & 1u)) >> 16);
}
__device__ __forceinline__ float bf2f(ushort u) { return __uint_as_float(((unsigned)u) << 16); }
__device__ __forceinline__ float decode_max(unsigned u) {
    return __uint_as_float((u & 0x80000000u) ? (u ^ 0x80000000u) : ~u);
}

// ---- kernel 1: u1/u2/c1/c2 (blocks 0-1), zero scal max, wv_w -> bf16 (blocks 2-129) ----
__global__ __launch_bounds__(256) void prep_kernel(const float* __restrict__ w_w,
                            const float* __restrict__ w_b, const float* __restrict__ a,
                            const float* __restrict__ wv_w,
                            float* __restrict__ u1, float* __restrict__ u2,
                            float* __restrict__ scal, ushort* __restrict__ wvbf) {
    int bid = blockIdx.x, t = threadIdx.x;
    if (bid < 2) {
        int d = bid * 256 + t;
        float s1 = 0.f, s2 = 0.f;
        for (int k = 0; k < DK_; ++k) {
            float w = w_w[k * DIM_ + d];
            s1 += w * a[k];
            s2 += w * a[DK_ + k];
        }
        u1[d] = s1; u2[d] = s2;
        if (d == 0) { float c = 0.f; for (int k = 0; k < DK_; ++k) c += w_b[k] * a[k];        scal[0] = c; }
        if (d == 1) { float c = 0.f; for (int k = 0; k < DK_; ++k) c += w_b[k] * a[DK_ + k];  scal[1] = c; }
        if (d == 2) ((unsigned*)scal)[3] = 0u;
    } else {
        int idx = (bid - 2) * 2048 + t * 8;
        f32x4 lo = *(const f32x4*)(wv_w + idx);
        f32x4 hi = *(const f32x4*)(wv_w + idx + 4);
        short8 f;
#pragma unroll
        for (int e = 0; e < 4; ++e) { f[e] = (short)f2bf(lo[e]); f[e + 4] = (short)f2bf(hi[e]); }
        *(short8*)(wvbf + idx) = f;
    }
}

// ---- kernel 2: e_src[i], e_dst[i], bf16 copy of x, zero rank/ki/res ----
__global__ __launch_bounds__(256) void e_kernel(const float* __restrict__ x,
        const float* __restrict__ u1, const float* __restrict__ u2,
        const float* __restrict__ scal, float* __restrict__ e_src, float* __restrict__ e_dst,
        ushort* __restrict__ xbf, int* __restrict__ rank, int* __restrict__ ki,
        int* __restrict__ res) {
    int wid = threadIdx.x >> 6, lane = threadIdx.x & 63;
    int row = blockIdx.x * 4 + wid;
    const float* xr = x + (size_t)row * DIM_;
    int d0 = lane * 8;
    f32x4 xa = *(const f32x4*)(xr + d0);
    f32x4 xb = *(const f32x4*)(xr + d0 + 4);
    f32x4 ua = *(const f32x4*)(u1 + d0);
    f32x4 ub = *(const f32x4*)(u1 + d0 + 4);
    f32x4 va = *(const f32x4*)(u2 + d0);
    f32x4 vb = *(const f32x4*)(u2 + d0 + 4);
    short8 xv;
#pragma unroll
    for (int e = 0; e < 4; ++e) { xv[e] = (short)f2bf(xa[e]); xv[e + 4] = (short)f2bf(xb[e]); }
    *(short8*)(xbf + (size_t)row * DIM_ + d0) = xv;
    float s1 = 0.f, s2 = 0.f;
#pragma unroll
    for (int e = 0; e < 4; ++e) {
        s1 += xa[e] * ua[e] + xb[e] * ub[e];
        s2 += xa[e] * va[e] + xb[e] * vb[e];
    }
    for (int off = 32; off; off >>= 1) { s1 += __shfl_xor(s1, off); s2 += __shfl_xor(s2, off); }
    if (lane == 0) {
        e_src[row] = s1 + scal[0];
        e_dst[row] = s2 + scal[1];
    }
    if (lane == 1) rank[row] = 0;
    if (lane == 2) ki[row] = 0;
    if (lane == 3) res[row] = 0;
}

// ---- kernel 3 (fused): blocks 0-511 = counting ranks (+max); blocks 512-767 = V GEMM ----
__global__ __launch_bounds__(256) void rankv_kernel(const float* __restrict__ e_dst,
        const float* __restrict__ e_src, int* __restrict__ rank, int* __restrict__ ki,
        int* __restrict__ res, float* __restrict__ scal,
        const ushort* __restrict__ xbf, const ushort* __restrict__ wvbf,
        const float* __restrict__ wv_b, ushort* __restrict__ V) {
    int bid = blockIdx.x, t = threadIdx.x;
    if (bid < 512) {
        __shared__ float ed[512];
        __shared__ float esl[512];
        __shared__ float red[4];
        int bx = bid & 31, by = bid >> 5;
        int rbase = by * 512;
        for (int q = t; q < 512; q += 256) { ed[q] = e_dst[rbase + q]; esl[q] = e_src[rbase + q]; }
        __syncthreads();
        if (bx == 0) {
            float m = fmaxf(ed[t], ed[t + 256]);
            for (int off = 32; off; off >>= 1) m = fmaxf(m, __shfl_xor(m, off));
            if ((t & 63) == 0) red[t >> 6] = m;
            __syncthreads();
            if (t == 0) {
                m = fmaxf(fmaxf(red[0], red[1]), fmaxf(red[2], red[3]));
                unsigned u = __float_as_uint(m);
                u ^= (unsigned)(((int)u >> 31)) | 0x80000000u;
                atomicMax(((unsigned*)scal) + 3, u);
            }
        }
        int j = bx * 256 + t;
        float kj = e_dst[j];
        float kei = -e_src[j];
        float kes = e_src[j];
        int cj = 0, ci = 0, ce = 0;
#pragma unroll 8
        for (int q = 0; q < 512; ++q) {
            float v = ed[q];
            float w = esl[q];
            int r = rbase + q;
            cj += (v < kj) || (v == kj && r < j);
            ci += (v < kei);
            ce += (w < kes) || (w == kes && r < j);
        }
        atomicAdd(rank + j, cj);
        atomicAdd(ki + j, ci);
        atomicAdd(res + j, ce);
    } else {
        int vb = bid - 512;
        int wid = t >> 6, lane = t & 63;
        int ln16 = lane & 15, kg = lane >> 4;
        int jb = (vb & 31) * 256 + wid * 64;
        int cb = (vb >> 5) * 64;
        f32x4 acc[4][4] = {};
        float bias[4];
#pragma unroll
        for (int ng = 0; ng < 4; ++ng) bias[ng] = wv_b[cb + ng * 16 + ln16];
        for (int k0 = 0; k0 < DIM_; k0 += 32) {
            int kk = k0 + kg * 8;
            short8 afr[4], bfr[4];
#pragma unroll
            for (int mg = 0; mg < 4; ++mg)
                afr[mg] = *(const short8*)(xbf + (size_t)(jb + mg * 16 + ln16) * DIM_ + kk);
#pragma unroll
            for (int ng = 0; ng < 4; ++ng)
                bfr[ng] = *(const short8*)(wvbf + (size_t)(cb + ng * 16 + ln16) * DIM_ + kk);
#pragma unroll
            for (int mg = 0; mg < 4; ++mg)
#pragma unroll
                for (int ng = 0; ng < 4; ++ng)
                    acc[mg][ng] = __builtin_amdgcn_mfma_f32_16x16x32_bf16(afr[mg], bfr[ng], acc[mg][ng], 0, 0, 0);
        }
#pragma unroll
        for (int mg = 0; mg < 4; ++mg)
#pragma unroll
            for (int ng = 0; ng < 4; ++ng)
#pragma unroll
                for (int r = 0; r < 4; ++r) {
                    int j = jb + mg * 16 + kg * 4 + r;
                    int c = cb + ng * 16 + ln16;
                    V[(size_t)j * DV_ + c] = f2bf(acc[mg][ng][r] + bias[ng]);
                }
    }
}

// ---- kernel 4: scatter perm, perm_es, G factors; also per-row F factors FF[j]={F1,F2} ----
__global__ __launch_bounds__(256) void scatter_kernel(const float* __restrict__ e_dst,
        const float* __restrict__ e_src,
        const int* __restrict__ rank, const int* __restrict__ res, const float* __restrict__ scal,
        int* __restrict__ perm, int* __restrict__ perm_es,
        float* __restrict__ Gs1, float* __restrict__ Gs2, f32x2* __restrict__ FF) {
    int j = blockIdx.x * 256 + threadIdx.x;
    float M = decode_max(((const unsigned*)scal)[3]);
    int rk = rank[j];
    float d = (e_dst[j] - M) * L2E_;
    perm[rk] = j;
    perm_es[res[j]] = j;
    Gs1[rk] = fexp2(d);
    Gs2[rk] = fexp2(0.01f * d);
    float tt = e_src[j] + M;
    float m = fmaxf(tt, 0.01f * tt);
    f32x2 f;
    f[0] = fexp2((tt - m) * L2E_);          // F1
    f[1] = fexp2((0.01f * tt - m) * L2E_);  // F2
    FF[j] = f;
}

// ---- kernel 5: local scans + chunk totals. Pk[k][c] = (bf16 A2loc_excl | bf16 S1loc_incl<<16) ----
__global__ __launch_bounds__(256) void p1_kernel(const ushort* __restrict__ V,
        const int* __restrict__ perm, const float* __restrict__ Gs1, const float* __restrict__ Gs2,
        unsigned* __restrict__ Pk, float* __restrict__ C1, float* __restrict__ C2,
        float* __restrict__ C1z, float* __restrict__ C2z,
        float* __restrict__ zl2, float* __restrict__ zl1) {
    int ch = blockIdx.x >> 1, half = blockIdx.x & 1;
    int t = threadIdx.x;
    int c = half * 256 + t;
    int k0 = ch * CHR_;
    int   jj[CHR_];
    float g1[CHR_], g2[CHR_], v[CHR_];
#pragma unroll
    for (int r = 0; r < CHR_; ++r) { jj[r] = perm[k0 + r]; g1[r] = Gs1[k0 + r]; g2[r] = Gs2[k0 + r]; }
#pragma unroll
    for (int r = 0; r < CHR_; ++r) v[r] = bf2f(V[(size_t)jj[r] * DV_ + c]);
    float t1 = 0.f, t2 = 0.f;
#pragma unroll
    for (int r = 0; r < CHR_; ++r) { t1 += g1[r] * v[r]; t2 += g2[r] * v[r]; }
    float r2 = 0.f, p1r = 0.f;
#pragma unroll
    for (int r = 0; r < CHR_; ++r) {
        Pk[(size_t)(k0 + r) * DV_ + c] = (unsigned)f2bf(r2) | ((unsigned)f2bf(t1 - p1r) << 16);
        r2 += g2[r] * v[r]; p1r += g1[r] * v[r];
    }
    C1[ch * 512 + c] = t1; C2[ch * 512 + c] = t2;
    if (half == 0 && t == 0) {
        float z1t = 0.f, z2t = 0.f;
#pragma unroll
        for (int r = 0; r < CHR_; ++r) { z1t += g1[r]; z2t += g2[r]; }
        C1z[ch] = z1t; C2z[ch] = z2t;
        float zp2 = 0.f, zp1 = 0.f;
#pragma unroll
        for (int r = 0; r < CHR_; ++r) {
            zl2[k0 + r] = zp2; zl1[k0 + r] = z1t - zp1;
            zp2 += g2[r]; zp1 += g1[r];
        }
    }
    if (ch == NCH_ - 1) {
        Pk[(size_t)N_ * DV_ + c] = 0u;
        if (half == 0 && t == 0) { zl2[N_] = 0.f; zl1[N_] = 0.f; }
    }
}

// ---- kernel 6: carries. b<64: excl prefix C2; b<128: excl suffix C1; b=128/129: z ----
__global__ __launch_bounds__(256) void p2_kernel(const float* __restrict__ C1,
        const float* __restrict__ C2, const float* __restrict__ C1z, const float* __restrict__ C2z,
        float* __restrict__ pc2, float* __restrict__ scs,
        float* __restrict__ zc2, float* __restrict__ zc1) {
    int b = blockIdx.x, t = threadIdx.x;
    if (b < 64) {
        int colL = t >> 5, s = t & 31;
        int c = b * 8 + colL;
        int base = s * 16;
        float v[16]; float seg = 0.f;
#pragma unroll
        for (int q = 0; q < 16; ++q) { v[q] = C2[(base + q) * 512 + c]; seg += v[q]; }
        float x = seg;
#pragma unroll
        for (int d = 1; d < 32; d <<= 1) { float y = __shfl_up(x, d, 32); if (s >= d) x += y; }
        float run = x - seg;
#pragma unroll
        for (int q = 0; q < 16; ++q) { pc2[(base + q) * 512 + c] = run; run += v[q]; }
        if (s == 31) pc2[NCH_ * 512 + c] = run;
    } else if (b < 128) {
        int colL = t >> 5, s = t & 31;
        int c = (b - 64) * 8 + colL;
        int base = s * 16;
        float v[16]; float seg = 0.f;
#pragma unroll
        for (int q = 0; q < 16; ++q) { v[q] = C1[(base + q) * 512 + c]; seg += v[q]; }
        float x = seg;
#pragma unroll
        for (int d = 1; d < 32; d <<= 1) { float y = __shfl_down(x, d, 32); if (s + d < 32) x += y; }
        float fwd = 0.f;
#pragma unroll
        for (int q = 0; q < 16; ++q) { fwd += v[q]; scs[(base + q) * 512 + c] = x - fwd; }
        if (s == 31) scs[NCH_ * 512 + c] = 0.f;
    } else {
        __shared__ float wt[4];
        bool pre = (b == 128);
        float v0 = pre ? C2z[t * 2] : C1z[t * 2];
        float v1 = pre ? C2z[t * 2 + 1] : C1z[t * 2 + 1];
        float seg = v0 + v1;
        int lane = t & 63, w = t >> 6;
        float x = seg;
        if (pre) {
#pragma unroll
            for (int d = 1; d < 64; d <<= 1) { float y = __shfl_up(x, d); if (lane >= d) x += y; }
            if (lane == 63) wt[w] = x;
        } else {
#pragma unroll
            for (int d = 1; d < 64; d <<= 1) { float y = __shfl_down(x, d); if (lane + d < 64) x += y; }
            if (lane == 0) wt[w] = x;
        }
        __syncthreads();
        float off = 0.f;
        if (pre) {
            for (int u = 0; u < w; ++u) off += wt[u];
            float run = off + (x - seg);
            zc2[t * 2] = run; run += v0; zc2[t * 2 + 1] = run;
            if (t == 255) zc2[NCH_] = off + x;
        } else {
            for (int u = w + 1; u < 4; ++u) off += wt[u];
            float S = off + x;                 // inclusive suffix from chunk t*2
            zc1[t * 2]     = S - v0;           // exclusive
            zc1[t * 2 + 1] = S - v0 - v1;
            if (t == 255) zc1[NCH_] = 0.f;
        }
    }
}

// ---- kernel 7: out rows in es-rank order; 2048 blocks x 4 rows; F from FF ----
__global__ __launch_bounds__(256) void out_kernel(const f32x2* __restrict__ FF,
        const int* __restrict__ ki, const int* __restrict__ perm_es,
        const float* __restrict__ zl2, const float* __restrict__ zl1,
        const float* __restrict__ zc2, const float* __restrict__ zc1,
        const float* __restrict__ pc2, const float* __restrict__ scs,
        const unsigned* __restrict__ Pk, float* __restrict__ out) {
    int t = threadIdx.x;
    int idx0 = blockIdx.x * 4;
    int c2 = t * 2;
#pragma unroll
    for (int q = 0; q < 4; ++q) {
        int i = perm_es[idx0 + q];
        f32x2 f = FF[i];
        float F1 = f[0], F2 = f[1];
        int lo = ki[i];
        int ch = lo >> 4;
        float z = F2 * (zc2[ch] + zl2[lo]) + F1 * (zc1[ch] + zl1[lo]);
        float rz = 1.0f / z;
        float al = F2 * rz, be = F1 * rz;
        u32x2 w = *(const u32x2*)(Pk + (size_t)lo * DV_ + c2);
        f32x2 cp = *(const f32x2*)(pc2 + ch * 512 + c2);
        f32x2 cs = *(const f32x2*)(scs + ch * 512 + c2);
        float o0 = al * (cp[0] + bf2f((ushort)(w[0] & 0xFFFFu))) + be * (cs[0] + bf2f((ushort)(w[0] >> 16)));
        float o1 = al * (cp[1] + bf2f((ushort)(w[1] & 0xFFFFu))) + be * (cs[1] + bf2f((ushort)(w[1] >> 16)));
        out[(size_t)i * DV_ + c2]     = o0;
        out[(size_t)i * DV_ + c2 + 1] = o1;
    }
}

extern "C" void kernel_launch(void* const* d_in, const int* in_sizes, int n_in,
                              void* d_out, int out_size, void* d_ws, size_t ws_size,
                              hipStream_t stream) {
    const float* x    = (const float*)d_in[0];
    const float* w_w  = (const float*)d_in[1];
    const float* w_b  = (const float*)d_in[2];
    const float* wv_w = (const float*)d_in[3];
    const float* wv_b = (const float*)d_in[4];
    const float* a    = (const float*)d_in[5];
    float* out = (float*)d_out;
    char* ws = (char*)d_ws;

    ushort*   V    = (ushort*)(ws);                      // 8 MiB
    ushort*   xbf  = (ushort*)(ws + 8388608);            // 8 MiB
    unsigned* Pk   = (unsigned*)(ws + 16777216);         // (N+1)*512*4 = 16,779,264
    char*     sm   = ws + 35651584;                      // small-array region
    float*  u1      = (float*)(sm);
    float*  u2      = (float*)(sm + 2048);
    float*  e_src   = (float*)(sm + 4096);
    float*  e_dst   = (float*)(sm + 36864);
    float*  scal    = (float*)(sm + 69632);              // [0]=c1 [1]=c2 [3]=max(uint)
    float*  Gs1     = (float*)(sm + 69888);
    float*  Gs2     = (float*)(sm + 102656);
    float*  C1      = (float*)(sm + 135424);             // 512*512*4 = 1 MiB
    float*  C2      = (float*)(sm + 1184000);
    float*  pc2     = (float*)(sm + 2232576);            // 513*512*4 (pad to 1,051,648)
    float*  scs     = (float*)(sm + 3284224);
    float*  C1z     = (float*)(sm + 4335872);            // 2 KiB
    float*  C2z     = (float*)(sm + 4337920);
    float*  zl2     = (float*)(sm + 4339968);            // 8193 f (pad 33024)
    float*  zl1     = (float*)(sm + 4372992);
    float*  zc2     = (float*)(sm + 4406016);            // 513 f (pad 4096)
    float*  zc1     = (float*)(sm + 4410112);
    int*    perm    = (int*)  (sm + 4414208);
    int*    rank    = (int*)  (sm + 4446976);
    int*    ki      = (int*)  (sm + 4479744);
    int*    res     = (int*)  (sm + 4512512);
    int*    perm_es = (int*)  (sm + 4545280);
    f32x2*  FF      = (f32x2*)(sm + 4578048);            // 64 KiB
    ushort* wvbf    = (ushort*)(sm + 4643584);           // 512 KiB

    hipLaunchKernelGGL(prep_kernel,    dim3(130),     dim3(256), 0, stream, w_w, w_b, a, wv_w, u1, u2, scal, wvbf);
    hipLaunchKernelGGL(e_kernel,       dim3(N_ / 4),  dim3(256), 0, stream, x, u1, u2, scal, e_src, e_dst, xbf, rank, ki, res);
    hipLaunchKernelGGL(rankv_kernel,   dim3(768),     dim3(256), 0, stream, e_dst, e_src, rank, ki, res, scal, xbf, wvbf, wv_b, V);
    hipLaunchKernelGGL(scatter_kernel, dim3(32),      dim3(256), 0, stream, e_dst, e_src, rank, res, scal, perm, perm_es, Gs1, Gs2, FF);
    hipLaunchKernelGGL(p1_kernel,      dim3(1024),    dim3(256), 0, stream, V, perm, Gs1, Gs2, Pk, C1, C2, C1z, C2z, zl2, zl1);
    hipLaunchKernelGGL(p2_kernel,      dim3(130),     dim3(256), 0, stream, C1, C2, C1z, C2z, pc2, scs, zc2, zc1);
    hipLaunchKernelGGL(out_kernel,     dim3(N_ / 4),  dim3(256), 0, stream, FF, ki, perm_es, zl2, zl1, zc2, zc1, pc2, scs, Pk, out);
}